// Round 2
// baseline (135.141 us; speedup 1.0000x reference)
//
#include <hip/hip_runtime.h>

#define NQ 6
#define HID 32
#define SNAPS 16
#define BATCH 1024
#define FSTRIDE 24       // floats per feature vector
#define FTOT 384         // 16 * 24
#define KSTR 24          // K-matrix LDS stride (16B-aligned, <=2-way conflicts = free)
#define KF   192         // per-f block: 8 cols/rows x 24

typedef float vfloat4 __attribute__((ext_vector_type(4)));   // for nontemporal stores

__device__ __forceinline__ float sigm_f(float x) { return 1.0f / (1.0f + __expf(-x)); }
__device__ __forceinline__ float tanh_f(float x) { return 1.0f - 2.0f / (__expf(2.0f * x) + 1.0f); }

__device__ __forceinline__ void rc_entry(float g, float b0, float b1, float b2,
                                         int i, int j, float& re, float& im) {
    // rc = (I + 3*shadow*B)/2, B = b0*sx + b1*sy + b2*sz ; g = 1.5*shadow
    if (i == j) { re = 0.5f + (i ? -g * b2 : g * b2); im = 0.0f; }
    else        { re = g * b0;  im = (i ? g * b1 : -g * b1); }
}

// ---------------------------------------------------------------------------
// Kernel 1: the 15-step LSTM chain. One batch element per 128-thread block:
// every thread owns one gate row, barriers sync only 2 waves, no idle waves.
// Feats (384 floats) are parked in the element's own out[] slice (scratch that
// recon_kernel fully overwrites) — block-private, so no cross-block hazard.
// ---------------------------------------------------------------------------
__global__ __launch_bounds__(128, 2)
void lstm_kernel(const float* __restrict__ snapshot,   // (B,6)
                 const float* __restrict__ bcv,        // (B,6,3)
                 const float* __restrict__ h0,         // (B,32)
                 const float* __restrict__ c0,         // (B,32)
                 const float* __restrict__ W_ih,       // (128,24)
                 const float* __restrict__ W_hh,       // (128,32)
                 const float* __restrict__ b_ih,       // (128)
                 const float* __restrict__ b_hh,       // (128)
                 const float* __restrict__ Wp,         // (6,32,3)
                 const float* __restrict__ bp,         // (6,3)
                 float* __restrict__ feat_scratch,     // = out; feat at b*8192
                 float* __restrict__ out_tail)         // (B,6,3)
{
    __shared__ __align__(16) float feat[FTOT];     // 1536 B
    __shared__ __align__(16) float sh[HID];
    __shared__ __align__(16) float sg[128];

    const int b = blockIdx.x;
    const int t = threadIdx.x;   // always < 128

    // per-row weights in registers (~56 VGPR)
    float4 wih[6], whh[8];
    {
        const float4* p = (const float4*)(W_ih + t * 24);
        #pragma unroll
        for (int k = 0; k < 6; ++k) wih[k] = p[k];
        const float4* q = (const float4*)(W_hh + t * 32);
        #pragma unroll
        for (int k = 0; k < 8; ++k) whh[k] = q[k];
    }
    const float bias = b_ih[t] + b_hh[t];

    float wp[32];
    float bpv = 0.0f, c = 0.0f;
    if (t < 18) {
        int q = t / 3, s = t - 3 * q;
        #pragma unroll
        for (int k = 0; k < 32; ++k) wp[k] = Wp[q * 96 + 3 * k + s];
        bpv = bp[t];
    }
    if (t < 32) { c = c0[b * 32 + t]; sh[t] = h0[b * 32 + t]; }
    if (t < 24) feat[t] = (t < 6) ? snapshot[b * 6 + t] : bcv[b * 18 + (t - 6)];
    __syncthreads();

    for (int step = 0; step < SNAPS - 1; ++step) {
        {   // gate row t: 4 independent FMA chains to cut serial depth
            const float4* x4 = (const float4*)(feat + step * FSTRIDE);  // broadcast
            const float4* h4 = (const float4*)sh;
            float ga = bias, gb = 0.0f, gc = 0.0f, gd = 0.0f;
            #pragma unroll
            for (int k = 0; k < 6; ++k) {
                float4 xq = x4[k];
                ga += xq.x * wih[k].x + xq.y * wih[k].y;
                gb += xq.z * wih[k].z + xq.w * wih[k].w;
            }
            #pragma unroll
            for (int k = 0; k < 8; ++k) {
                float4 hq = h4[k];
                gc += hq.x * whh[k].x + hq.y * whh[k].y;
                gd += hq.z * whh[k].z + hq.w * whh[k].w;
            }
            sg[t] = (ga + gb) + (gc + gd);
        }
        __syncthreads();

        if (t < 64) {   // wave 0 only: activation + projection + softmax
            if (t < 32) {
                float gi = sg[t], gf = sg[32 + t], gg = sg[64 + t], go = sg[96 + t];
                c = sigm_f(gf) * c + sigm_f(gi) * tanh_f(gg);
                sh[t] = sigm_f(go) * tanh_f(c);
            }
            __builtin_amdgcn_wave_barrier();   // order in-wave DS: sh write -> reads below
            // projection: lanes 0..17 (others compute garbage, discarded)
            // two independent chains: serial FMA depth 16 instead of 32
            float lg0 = bpv, lg1 = 0.0f;
            const float4* h4b = (const float4*)sh;
            #pragma unroll
            for (int k = 0; k < 4; ++k) {
                float4 hq = h4b[k];
                lg0 += hq.x * wp[4 * k] + hq.y * wp[4 * k + 1]
                     + hq.z * wp[4 * k + 2] + hq.w * wp[4 * k + 3];
            }
            #pragma unroll
            for (int k = 4; k < 8; ++k) {
                float4 hq = h4b[k];
                lg1 += hq.x * wp[4 * k] + hq.y * wp[4 * k + 1]
                     + hq.z * wp[4 * k + 2] + hq.w * wp[4 * k + 3];
            }
            float logit = lg0 + lg1;
            int q3 = 3 * (t < 6 ? t : 0);
            float l0 = __shfl(logit, q3), l1 = __shfl(logit, q3 + 1), l2 = __shfl(logit, q3 + 2);
            if (t < 6) {
                float m = fmaxf(l0, fmaxf(l1, l2));
                float e0 = __expf(l0 - m), e1 = __expf(l1 - m), e2 = __expf(l2 - m);
                float inv = 1.0f / (e0 + e1 + e2);
                float p0 = e0 * inv, p1 = e1 * inv, p2 = e2 * inv;
                float snap = p0 * p0 + p1 * p1 + p2 * p2;  // tr(M rho Mdag)=sum p^2 (rho unused)
                float* fd = feat + (step + 1) * FSTRIDE;
                fd[t] = snap;
                fd[6 + 3 * t]     = p0;
                fd[6 + 3 * t + 1] = p1;
                fd[6 + 3 * t + 2] = p2;
            }
        }
        __syncthreads();
    }

    // park feats in this element's out-slice (overwritten by recon_kernel)
    if (t < 96)
        ((float4*)(feat_scratch + (size_t)b * 8192))[t] = ((const float4*)feat)[t];
    // tail output: bv of last feature = final probs
    if (t < 18) out_tail[b * 18 + t] = feat[15 * FSTRIDE + 6 + t];
}

// ---------------------------------------------------------------------------
// Kernel 2: shadow reconstruction. Identical math/layout to the verified
// fused phase 2; feats come from the scratch region of out (then overwritten).
// No __restrict__ on feat_src/out: they alias (reads precede writes within a
// block; regions are block-private).
// ---------------------------------------------------------------------------
__global__ __launch_bounds__(256, 4)   // cap 128 VGPR, 4 blocks/CU
void recon_kernel(const float* feat_src,   // = out; feat at b*8192
                  float* out)              // (B,2,64,64)
{
    __shared__ __align__(16) float sKA[16 * KF];   // 12 KB
    __shared__ __align__(16) float sKB[16 * KF];   // 12 KB
    __shared__ __align__(16) float feat[FTOT];     // 1.5 KB

    const int b = blockIdx.x;
    const int t = threadIdx.x;

    if (t < 96)
        ((float4*)feat)[t] = ((const float4*)(feat_src + (size_t)b * 8192))[t];
    __syncthreads();

    // ---- build KA/KB: 2048 entries, 8 per thread ----
    for (int n = t; n < 2048; n += 256) {
        int f = n >> 7, r = n & 127;
        int half = r >> 6, a = r & 63;
        const float* fx = &feat[f * FSTRIDE];
        int i0 = (a >> 5) & 1, i1 = (a >> 4) & 1, i2 = (a >> 3) & 1;
        int j0 = (a >> 2) & 1, j1 = (a >> 1) & 1, j2 = a & 1;
        int q = 3 * half;
        float g0 = 1.5f * fx[q], g1 = 1.5f * fx[q + 1], g2 = 1.5f * fx[q + 2];
        const float* bb = fx + 6 + 3 * q;
        float r0, m0, r1, m1, r2, m2;
        rc_entry(g0, bb[0], bb[1], bb[2], i0, j0, r0, m0);
        rc_entry(g1, bb[3], bb[4], bb[5], i1, j1, r1, m1);
        rc_entry(g2, bb[6], bb[7], bb[8], i2, j2, r2, m2);
        float pr = r0 * r1 - m0 * m1, pi = r0 * m1 + m0 * r1;
        float qr = pr * r2 - pi * m2, qi = pr * m2 + pi * r2;
        int row = a >> 3, col = a & 7;
        if (half == 0) {
            // KA: col-major, rows grouped by parity (even at [0..7], odd at [8..15])
            int off = f * KF + col * KSTR + ((row & 1) ? (7 + row) : row);
            sKA[off] = qr; sKA[off + 1] = qi;
        } else {
            int off = f * KF + row * KSTR + 2 * col;
            sKB[off] = qr; sKB[off + 1] = qi;
        }
    }
    __syncthreads();

    // ---- accumulate: out[i][j] = (1/16) sum_f KA[i>>3][j>>3] * KB[i&7][j&7]
    // thread t: u=t&15, v=t>>4; i = v+16e (e<4), j = 4u+d (d<4)
    const int u = t & 15, v = t >> 4;
    const float* baseA = sKA + (u >> 1) * KSTR + 8 * (v >> 3);   // col jA, parity group
    const float* baseB = sKB + (v & 7) * KSTR + 8 * (u & 1);     // row iB, col group
    float accr[4][4], acci[4][4];
    #pragma unroll
    for (int e = 0; e < 4; ++e)
        #pragma unroll
        for (int d = 0; d < 4; ++d) { accr[e][d] = 0.0f; acci[e][d] = 0.0f; }

    #pragma unroll 2   // keep hoisted LDS loads within the 128-VGPR budget (no scratch!)
    for (int f = 0; f < SNAPS; ++f) {
        float4 A0 = *(const float4*)(baseA + f * KF);
        float4 A1 = *(const float4*)(baseA + f * KF + 4);
        float4 B0 = *(const float4*)(baseB + f * KF);
        float4 B1 = *(const float4*)(baseB + f * KF + 4);
        float ar[4] = {A0.x, A0.z, A1.x, A1.z};    // iA = 2e + (v>>3)
        float ai[4] = {A0.y, A0.w, A1.y, A1.w};
        float br[4] = {B0.x, B0.z, B1.x, B1.z};    // jB = 4(u&1) + d
        float bi[4] = {B0.y, B0.w, B1.y, B1.w};
        #pragma unroll
        for (int e = 0; e < 4; ++e)
            #pragma unroll
            for (int d = 0; d < 4; ++d) {
                accr[e][d] += ar[e] * br[d] - ai[e] * bi[d];
                acci[e][d] += ar[e] * bi[d] + ai[e] * br[d];
            }
    }

    const float s = 1.0f / 16.0f;
    float* outb = out + (size_t)b * 8192;
    #pragma unroll
    for (int e = 0; e < 4; ++e) {
        int i = v + 16 * e;
        vfloat4 r4 = { accr[e][0] * s, accr[e][1] * s, accr[e][2] * s, accr[e][3] * s };
        vfloat4 i4 = { acci[e][0] * s, acci[e][1] * s, acci[e][2] * s, acci[e][3] * s };
        __builtin_nontemporal_store(r4, (vfloat4*)(outb + i * 64 + 4 * u));
        __builtin_nontemporal_store(i4, (vfloat4*)(outb + 4096 + i * 64 + 4 * u));
    }
}

extern "C" void kernel_launch(void* const* d_in, const int* in_sizes, int n_in,
                              void* d_out, int out_size, void* d_ws, size_t ws_size,
                              hipStream_t stream) {
    const float* snapshot = (const float*)d_in[0];
    const float* bcv      = (const float*)d_in[1];
    // d_in[2] = rho — unused: tr(M rho M^dag) = (sum_s p_s^2) tr(rho), tr(rho)=1
    const float* h0       = (const float*)d_in[3];
    const float* c0       = (const float*)d_in[4];
    const float* W_ih     = (const float*)d_in[5];
    const float* W_hh     = (const float*)d_in[6];
    const float* b_ih     = (const float*)d_in[7];
    const float* b_hh     = (const float*)d_in[8];
    const float* Wp       = (const float*)d_in[9];
    const float* bp       = (const float*)d_in[10];
    // d_in[11], d_in[12] = basis_r, basis_i — folded into rc_entry
    float* out = (float*)d_out;

    lstm_kernel<<<BATCH, 128, 0, stream>>>(
        snapshot, bcv, h0, c0, W_ih, W_hh, b_ih, b_hh, Wp, bp,
        out /*feat scratch*/, out + (size_t)BATCH * 8192 /*tail*/);
    recon_kernel<<<BATCH, 256, 0, stream>>>(out, out);
}

// Round 3
// 133.228 us; speedup vs baseline: 1.0144x; 1.0144x over previous
//
#include <hip/hip_runtime.h>

#define NQ 6
#define HID 32
#define SNAPS 16
#define BATCH 1024
#define FSTRIDE 24       // floats per feature vector
#define FTOT 384         // 16 * 24
#define KSTR 24          // K-matrix LDS stride (16B-aligned, <=2-way conflicts = free)
#define KF   192         // per-f block: 8 cols/rows x 24

typedef float vfloat4 __attribute__((ext_vector_type(4)));   // for nontemporal stores

__device__ __forceinline__ float sigm_f(float x) { return 1.0f / (1.0f + __expf(-x)); }
__device__ __forceinline__ float tanh_f(float x) { return 1.0f - 2.0f / (__expf(2.0f * x) + 1.0f); }

// readlane -> wave-uniform value (SGPR): lets FMAs consume broadcast h/x directly
__device__ __forceinline__ float rl(float v, int l) {
    return __builtin_bit_cast(float, __builtin_amdgcn_readlane(__builtin_bit_cast(int, v), l));
}

__device__ __forceinline__ void rc_entry(float g, float b0, float b1, float b2,
                                         int i, int j, float& re, float& im) {
    // rc = (I + 3*shadow*B)/2, B = b0*sx + b1*sy + b2*sz ; g = 1.5*shadow
    if (i == j) { re = 0.5f + (i ? -g * b2 : g * b2); im = 0.0f; }
    else        { re = g * b0;  im = (i ? g * b1 : -g * b1); }
}

// ---------------------------------------------------------------------------
// Kernel 1: 15-step LSTM, ONE WAVE per batch element. Lane t owns gate rows
// t and t+64 (weights in VGPRs). h and x live as wave-uniform SGPRs via
// v_readlane broadcast; gf/go come from lane t+32 via 2 shuffles. No LDS on
// the recurrence critical path, no __syncthreads at all. feat LDS is
// write-only until the epilogue park to global scratch.
// ---------------------------------------------------------------------------
__global__ __launch_bounds__(64)
void lstm_kernel(const float* __restrict__ snapshot,   // (B,6)
                 const float* __restrict__ bcv,        // (B,6,3)
                 const float* __restrict__ h0,         // (B,32)
                 const float* __restrict__ c0,         // (B,32)
                 const float* __restrict__ W_ih,       // (128,24)
                 const float* __restrict__ W_hh,       // (128,32)
                 const float* __restrict__ b_ih,       // (128)
                 const float* __restrict__ b_hh,       // (128)
                 const float* __restrict__ Wp,         // (6,32,3)
                 const float* __restrict__ bp,         // (6,3)
                 float* __restrict__ feat_scratch,     // = out; feat at b*8192
                 float* __restrict__ out_tail)         // (B,6,3)
{
    __shared__ __align__(16) float feat[FTOT];     // 1536 B, write-only until park

    const int b = blockIdx.x;
    const int t = threadIdx.x;   // 0..63, single wave

    // ---- weights for rows t and t+64 in VGPRs (112 VGPR) ----
    float4 wih0[6], wih1[6], whh0[8], whh1[8];
    {
        const float4* p0 = (const float4*)(W_ih + t * 24);
        const float4* p1 = (const float4*)(W_ih + (t + 64) * 24);
        #pragma unroll
        for (int k = 0; k < 6; ++k) { wih0[k] = p0[k]; wih1[k] = p1[k]; }
        const float4* q0 = (const float4*)(W_hh + t * 32);
        const float4* q1 = (const float4*)(W_hh + (t + 64) * 32);
        #pragma unroll
        for (int k = 0; k < 8; ++k) { whh0[k] = q0[k]; whh1[k] = q1[k]; }
    }
    const float bias0 = b_ih[t] + b_hh[t];
    const float bias1 = b_ih[t + 64] + b_hh[t + 64];

    float wp[32];
    float bpv = 0.0f, cst = 0.0f;
    if (t < 18) {
        int q = t / 3, s = t - 3 * q;
        #pragma unroll
        for (int k = 0; k < 32; ++k) wp[k] = Wp[q * 96 + 3 * k + s];
        bpv = bp[t];
    } else {
        #pragma unroll
        for (int k = 0; k < 32; ++k) wp[k] = 0.0f;   // keep garbage out of exp()
    }
    if (t < 32) cst = c0[b * 32 + t];

    // ---- initial h, x broadcast into uniform (SGPR) arrays ----
    float hval = (t < 32) ? h0[b * 32 + t] : 0.0f;
    float shh[32], sx[24];
    #pragma unroll
    for (int k = 0; k < 32; ++k) shh[k] = rl(hval, k);

    float x0v = 0.0f;
    if (t < 24) x0v = (t < 6) ? snapshot[b * 6 + t] : bcv[b * 18 + (t - 6)];
    if (t < 24) feat[t] = x0v;
    #pragma unroll
    for (int k = 0; k < 24; ++k) sx[k] = rl(x0v, k);

    // ---- 15 steps, zero barriers ----
    for (int step = 0; step < SNAPS - 1; ++step) {
        // gate rows t (g0) and t+64 (g1): uniform(sx/shh) x VGPR weights
        float a0 = bias0, a1 = 0.0f, a2 = bias1, a3 = 0.0f;
        #pragma unroll
        for (int k = 0; k < 6; ++k) {
            a0 += sx[4 * k]     * wih0[k].x + sx[4 * k + 1] * wih0[k].y;
            a1 += sx[4 * k + 2] * wih0[k].z + sx[4 * k + 3] * wih0[k].w;
            a2 += sx[4 * k]     * wih1[k].x + sx[4 * k + 1] * wih1[k].y;
            a3 += sx[4 * k + 2] * wih1[k].z + sx[4 * k + 3] * wih1[k].w;
        }
        float a4 = 0.0f, a5 = 0.0f, a6 = 0.0f, a7 = 0.0f;
        #pragma unroll
        for (int k = 0; k < 8; ++k) {
            a4 += shh[4 * k]     * whh0[k].x + shh[4 * k + 1] * whh0[k].y;
            a5 += shh[4 * k + 2] * whh0[k].z + shh[4 * k + 3] * whh0[k].w;
            a6 += shh[4 * k]     * whh1[k].x + shh[4 * k + 1] * whh1[k].y;
            a7 += shh[4 * k + 2] * whh1[k].z + shh[4 * k + 3] * whh1[k].w;
        }
        float g0 = (a0 + a1) + (a4 + a5);   // row t:    gi[t]   (t<32) | gf[t-32]
        float g1 = (a2 + a3) + (a6 + a7);   // row t+64: gg[t]   (t<32) | go[t-32]

        // unit j=t (lanes 0-31): gf,go live on lane t+32 (wraps harmlessly for t>=32)
        float gf = __shfl(g0, (t + 32) & 63);
        float go = __shfl(g1, (t + 32) & 63);
        float gi = g0, gg = g1;

        // activation (meaningful on lanes 0-31; lanes 32-63 compute discard values)
        cst = sigm_f(gf) * cst + sigm_f(gi) * tanh_f(gg);
        hval = sigm_f(go) * tanh_f(cst);

        // h broadcast: 32 readlanes from lanes 0-31
        #pragma unroll
        for (int k = 0; k < 32; ++k) shh[k] = rl(hval, k);

        // projection (uniform h x VGPR wp), real only on lanes 0-17
        float lg0 = bpv, lg1 = 0.0f;
        #pragma unroll
        for (int k = 0; k < 16; ++k) lg0 += shh[k] * wp[k];
        #pragma unroll
        for (int k = 16; k < 32; ++k) lg1 += shh[k] * wp[k];
        float logit = lg0 + lg1;

        int q3 = 3 * (t < 6 ? t : 0);
        float l0 = __shfl(logit, q3), l1 = __shfl(logit, q3 + 1), l2 = __shfl(logit, q3 + 2);
        float m = fmaxf(l0, fmaxf(l1, l2));
        float e0 = __expf(l0 - m), e1 = __expf(l1 - m), e2 = __expf(l2 - m);
        float inv = 1.0f / (e0 + e1 + e2);
        float p0 = e0 * inv, p1 = e1 * inv, p2 = e2 * inv;
        float snap = p0 * p0 + p1 * p1 + p2 * p2;  // tr(M rho Mdag)=sum p^2 (rho unused)

        if (t < 6) {   // park this step's feature row (write-only LDS)
            float* fd = feat + (step + 1) * FSTRIDE;
            fd[t] = snap;
            fd[6 + 3 * t]     = p0;
            fd[6 + 3 * t + 1] = p1;
            fd[6 + 3 * t + 2] = p2;
        }

        // x broadcast for next step: 24 readlanes from lanes 0-5
        #pragma unroll
        for (int q = 0; q < 6; ++q) {
            sx[q]          = rl(snap, q);
            sx[6 + 3 * q]     = rl(p0, q);
            sx[6 + 3 * q + 1] = rl(p1, q);
            sx[6 + 3 * q + 2] = rl(p2, q);
        }
    }

    __builtin_amdgcn_wave_barrier();   // order feat ds_writes before park reads
    // park feats in this element's out-slice (overwritten by recon_kernel)
    float4* dst = (float4*)(feat_scratch + (size_t)b * 8192);
    const float4* srcf = (const float4*)feat;
    dst[t] = srcf[t];
    if (t < 32) dst[64 + t] = srcf[64 + t];
    // tail output: bv of last feature = final probs
    if (t < 18) out_tail[b * 18 + t] = feat[15 * FSTRIDE + 6 + t];
}

// ---------------------------------------------------------------------------
// Kernel 2: shadow reconstruction — UNCHANGED (verified, store-bound).
// feats come from the scratch region of out (then overwritten). No __restrict__
// on feat_src/out: they alias.
// ---------------------------------------------------------------------------
__global__ __launch_bounds__(256, 4)   // cap 128 VGPR, 4 blocks/CU
void recon_kernel(const float* feat_src,   // = out; feat at b*8192
                  float* out)              // (B,2,64,64)
{
    __shared__ __align__(16) float sKA[16 * KF];   // 12 KB
    __shared__ __align__(16) float sKB[16 * KF];   // 12 KB
    __shared__ __align__(16) float feat[FTOT];     // 1.5 KB

    const int b = blockIdx.x;
    const int t = threadIdx.x;

    if (t < 96)
        ((float4*)feat)[t] = ((const float4*)(feat_src + (size_t)b * 8192))[t];
    __syncthreads();

    // ---- build KA/KB: 2048 entries, 8 per thread ----
    for (int n = t; n < 2048; n += 256) {
        int f = n >> 7, r = n & 127;
        int half = r >> 6, a = r & 63;
        const float* fx = &feat[f * FSTRIDE];
        int i0 = (a >> 5) & 1, i1 = (a >> 4) & 1, i2 = (a >> 3) & 1;
        int j0 = (a >> 2) & 1, j1 = (a >> 1) & 1, j2 = a & 1;
        int q = 3 * half;
        float g0 = 1.5f * fx[q], g1 = 1.5f * fx[q + 1], g2 = 1.5f * fx[q + 2];
        const float* bb = fx + 6 + 3 * q;
        float r0, m0, r1, m1, r2, m2;
        rc_entry(g0, bb[0], bb[1], bb[2], i0, j0, r0, m0);
        rc_entry(g1, bb[3], bb[4], bb[5], i1, j1, r1, m1);
        rc_entry(g2, bb[6], bb[7], bb[8], i2, j2, r2, m2);
        float pr = r0 * r1 - m0 * m1, pi = r0 * m1 + m0 * r1;
        float qr = pr * r2 - pi * m2, qi = pr * m2 + pi * r2;
        int row = a >> 3, col = a & 7;
        if (half == 0) {
            // KA: col-major, rows grouped by parity (even at [0..7], odd at [8..15])
            int off = f * KF + col * KSTR + ((row & 1) ? (7 + row) : row);
            sKA[off] = qr; sKA[off + 1] = qi;
        } else {
            int off = f * KF + row * KSTR + 2 * col;
            sKB[off] = qr; sKB[off + 1] = qi;
        }
    }
    __syncthreads();

    // ---- accumulate: out[i][j] = (1/16) sum_f KA[i>>3][j>>3] * KB[i&7][j&7]
    // thread t: u=t&15, v=t>>4; i = v+16e (e<4), j = 4u+d (d<4)
    const int u = t & 15, v = t >> 4;
    const float* baseA = sKA + (u >> 1) * KSTR + 8 * (v >> 3);   // col jA, parity group
    const float* baseB = sKB + (v & 7) * KSTR + 8 * (u & 1);     // row iB, col group
    float accr[4][4], acci[4][4];
    #pragma unroll
    for (int e = 0; e < 4; ++e)
        #pragma unroll
        for (int d = 0; d < 4; ++d) { accr[e][d] = 0.0f; acci[e][d] = 0.0f; }

    #pragma unroll 2   // keep hoisted LDS loads within the 128-VGPR budget (no scratch!)
    for (int f = 0; f < SNAPS; ++f) {
        float4 A0 = *(const float4*)(baseA + f * KF);
        float4 A1 = *(const float4*)(baseA + f * KF + 4);
        float4 B0 = *(const float4*)(baseB + f * KF);
        float4 B1 = *(const float4*)(baseB + f * KF + 4);
        float ar[4] = {A0.x, A0.z, A1.x, A1.z};    // iA = 2e + (v>>3)
        float ai[4] = {A0.y, A0.w, A1.y, A1.w};
        float br[4] = {B0.x, B0.z, B1.x, B1.z};    // jB = 4(u&1) + d
        float bi[4] = {B0.y, B0.w, B1.y, B1.w};
        #pragma unroll
        for (int e = 0; e < 4; ++e)
            #pragma unroll
            for (int d = 0; d < 4; ++d) {
                accr[e][d] += ar[e] * br[d] - ai[e] * bi[d];
                acci[e][d] += ar[e] * bi[d] + ai[e] * br[d];
            }
    }

    const float s = 1.0f / 16.0f;
    float* outb = out + (size_t)b * 8192;
    #pragma unroll
    for (int e = 0; e < 4; ++e) {
        int i = v + 16 * e;
        vfloat4 r4 = { accr[e][0] * s, accr[e][1] * s, accr[e][2] * s, accr[e][3] * s };
        vfloat4 i4 = { acci[e][0] * s, acci[e][1] * s, acci[e][2] * s, acci[e][3] * s };
        __builtin_nontemporal_store(r4, (vfloat4*)(outb + i * 64 + 4 * u));
        __builtin_nontemporal_store(i4, (vfloat4*)(outb + 4096 + i * 64 + 4 * u));
    }
}

extern "C" void kernel_launch(void* const* d_in, const int* in_sizes, int n_in,
                              void* d_out, int out_size, void* d_ws, size_t ws_size,
                              hipStream_t stream) {
    const float* snapshot = (const float*)d_in[0];
    const float* bcv      = (const float*)d_in[1];
    // d_in[2] = rho — unused: tr(M rho M^dag) = (sum_s p_s^2) tr(rho), tr(rho)=1
    const float* h0       = (const float*)d_in[3];
    const float* c0       = (const float*)d_in[4];
    const float* W_ih     = (const float*)d_in[5];
    const float* W_hh     = (const float*)d_in[6];
    const float* b_ih     = (const float*)d_in[7];
    const float* b_hh     = (const float*)d_in[8];
    const float* Wp       = (const float*)d_in[9];
    const float* bp       = (const float*)d_in[10];
    // d_in[11], d_in[12] = basis_r, basis_i — folded into rc_entry
    float* out = (float*)d_out;

    lstm_kernel<<<BATCH, 64, 0, stream>>>(
        snapshot, bcv, h0, c0, W_ih, W_hh, b_ih, b_hh, Wp, bp,
        out /*feat scratch*/, out + (size_t)BATCH * 8192 /*tail*/);
    recon_kernel<<<BATCH, 256, 0, stream>>>(out, out);
}

// Round 4
// 131.639 us; speedup vs baseline: 1.0266x; 1.0121x over previous
//
#include <hip/hip_runtime.h>

#define NQ 6
#define HID 32
#define SNAPS 16
#define BATCH 1024
#define FSTRIDE 24       // floats per feature vector
#define FTOT 384         // 16 * 24
#define KSTR 24          // K-matrix LDS stride (16B-aligned, <=2-way conflicts = free)
#define KF   192         // per-f block: 8 cols/rows x 24

typedef float vfloat4 __attribute__((ext_vector_type(4)));   // for nontemporal stores

__device__ __forceinline__ float sigm_f(float x) { return 1.0f / (1.0f + __expf(-x)); }
__device__ __forceinline__ float tanh_f(float x) { return 1.0f - 2.0f / (__expf(2.0f * x) + 1.0f); }

// readlane -> wave-uniform value (SGPR): lets FMAs consume broadcast h/x directly
__device__ __forceinline__ float rl(float v, int l) {
    return __builtin_bit_cast(float, __builtin_amdgcn_readlane(__builtin_bit_cast(int, v), l));
}

__device__ __forceinline__ void rc_entry(float g, float b0, float b1, float b2,
                                         int i, int j, float& re, float& im) {
    // rc = (I + 3*shadow*B)/2, B = b0*sx + b1*sy + b2*sz ; g = 1.5*shadow
    if (i == j) { re = 0.5f + (i ? -g * b2 : g * b2); im = 0.0f; }
    else        { re = g * b0;  im = (i ? g * b1 : -g * b1); }
}

// ---------------------------------------------------------------------------
// Single fused kernel, 128 threads (2 waves) per batch element.
// Phase 1: wave 0 runs the 15-step LSTM entirely in registers/SGPRs
//          (readlane broadcast, zero barriers), feats land in LDS.
// Phase 2: both waves build KA/KB and do the rank-16 complex accumulation;
//          each thread covers two row-halves (even/odd KA parity groups).
// ~26 KB LDS, ~170 VGPR -> ~6 blocks/CU -> all 1024 blocks resident.
// ---------------------------------------------------------------------------
__global__ __launch_bounds__(128)
void fused_kernel(const float* __restrict__ snapshot,   // (B,6)
                  const float* __restrict__ bcv,        // (B,6,3)
                  const float* __restrict__ h0,         // (B,32)
                  const float* __restrict__ c0,         // (B,32)
                  const float* __restrict__ W_ih,       // (128,24)
                  const float* __restrict__ W_hh,       // (128,32)
                  const float* __restrict__ b_ih,       // (128)
                  const float* __restrict__ b_hh,       // (128)
                  const float* __restrict__ Wp,         // (6,32,3)
                  const float* __restrict__ bp,         // (6,3)
                  float* __restrict__ out,              // (B,2,64,64)
                  float* __restrict__ out_tail)         // (B,6,3)
{
    __shared__ __align__(16) float sKA[16 * KF];   // 12 KB
    __shared__ __align__(16) float sKB[16 * KF];   // 12 KB
    __shared__ __align__(16) float feat[FTOT];     // 1.5 KB

    const int b = blockIdx.x;
    const int t = threadIdx.x;   // 0..127

    // ================= Phase 1: wave-0 LSTM (verified round-3 code) =========
    if (t < 64) {
        // weights for gate rows t and t+64 in VGPRs
        float4 wih0[6], wih1[6], whh0[8], whh1[8];
        {
            const float4* p0 = (const float4*)(W_ih + t * 24);
            const float4* p1 = (const float4*)(W_ih + (t + 64) * 24);
            #pragma unroll
            for (int k = 0; k < 6; ++k) { wih0[k] = p0[k]; wih1[k] = p1[k]; }
            const float4* q0 = (const float4*)(W_hh + t * 32);
            const float4* q1 = (const float4*)(W_hh + (t + 64) * 32);
            #pragma unroll
            for (int k = 0; k < 8; ++k) { whh0[k] = q0[k]; whh1[k] = q1[k]; }
        }
        const float bias0 = b_ih[t] + b_hh[t];
        const float bias1 = b_ih[t + 64] + b_hh[t + 64];

        float wp[32];
        float bpv = 0.0f, cst = 0.0f;
        if (t < 18) {
            int q = t / 3, s = t - 3 * q;
            #pragma unroll
            for (int k = 0; k < 32; ++k) wp[k] = Wp[q * 96 + 3 * k + s];
            bpv = bp[t];
        } else {
            #pragma unroll
            for (int k = 0; k < 32; ++k) wp[k] = 0.0f;   // keep garbage out of exp()
        }
        if (t < 32) cst = c0[b * 32 + t];

        float hval = (t < 32) ? h0[b * 32 + t] : 0.0f;
        float shh[32], sx[24];
        #pragma unroll
        for (int k = 0; k < 32; ++k) shh[k] = rl(hval, k);

        float x0v = 0.0f;
        if (t < 24) x0v = (t < 6) ? snapshot[b * 6 + t] : bcv[b * 18 + (t - 6)];
        if (t < 24) feat[t] = x0v;
        #pragma unroll
        for (int k = 0; k < 24; ++k) sx[k] = rl(x0v, k);

        for (int step = 0; step < SNAPS - 1; ++step) {
            float a0 = bias0, a1 = 0.0f, a2 = bias1, a3 = 0.0f;
            #pragma unroll
            for (int k = 0; k < 6; ++k) {
                a0 += sx[4 * k]     * wih0[k].x + sx[4 * k + 1] * wih0[k].y;
                a1 += sx[4 * k + 2] * wih0[k].z + sx[4 * k + 3] * wih0[k].w;
                a2 += sx[4 * k]     * wih1[k].x + sx[4 * k + 1] * wih1[k].y;
                a3 += sx[4 * k + 2] * wih1[k].z + sx[4 * k + 3] * wih1[k].w;
            }
            float a4 = 0.0f, a5 = 0.0f, a6 = 0.0f, a7 = 0.0f;
            #pragma unroll
            for (int k = 0; k < 8; ++k) {
                a4 += shh[4 * k]     * whh0[k].x + shh[4 * k + 1] * whh0[k].y;
                a5 += shh[4 * k + 2] * whh0[k].z + shh[4 * k + 3] * whh0[k].w;
                a6 += shh[4 * k]     * whh1[k].x + shh[4 * k + 1] * whh1[k].y;
                a7 += shh[4 * k + 2] * whh1[k].z + shh[4 * k + 3] * whh1[k].w;
            }
            float g0 = (a0 + a1) + (a4 + a5);   // row t:    gi[t] (t<32) | gf[t-32]
            float g1 = (a2 + a3) + (a6 + a7);   // row t+64: gg[t] (t<32) | go[t-32]

            float gf = __shfl(g0, (t + 32) & 63);
            float go = __shfl(g1, (t + 32) & 63);
            float gi = g0, gg = g1;

            cst = sigm_f(gf) * cst + sigm_f(gi) * tanh_f(gg);
            hval = sigm_f(go) * tanh_f(cst);

            #pragma unroll
            for (int k = 0; k < 32; ++k) shh[k] = rl(hval, k);

            float lg0 = bpv, lg1 = 0.0f;
            #pragma unroll
            for (int k = 0; k < 16; ++k) lg0 += shh[k] * wp[k];
            #pragma unroll
            for (int k = 16; k < 32; ++k) lg1 += shh[k] * wp[k];
            float logit = lg0 + lg1;

            int q3 = 3 * (t < 6 ? t : 0);
            float l0 = __shfl(logit, q3), l1 = __shfl(logit, q3 + 1), l2 = __shfl(logit, q3 + 2);
            float m = fmaxf(l0, fmaxf(l1, l2));
            float e0 = __expf(l0 - m), e1 = __expf(l1 - m), e2 = __expf(l2 - m);
            float inv = 1.0f / (e0 + e1 + e2);
            float p0 = e0 * inv, p1 = e1 * inv, p2 = e2 * inv;
            float snap = p0 * p0 + p1 * p1 + p2 * p2;  // tr(M rho Mdag)=sum p^2 (rho unused)

            if (t < 6) {
                float* fd = feat + (step + 1) * FSTRIDE;
                fd[t] = snap;
                fd[6 + 3 * t]     = p0;
                fd[6 + 3 * t + 1] = p1;
                fd[6 + 3 * t + 2] = p2;
            }

            #pragma unroll
            for (int q = 0; q < 6; ++q) {
                sx[q]             = rl(snap, q);
                sx[6 + 3 * q]     = rl(p0, q);
                sx[6 + 3 * q + 1] = rl(p1, q);
                sx[6 + 3 * q + 2] = rl(p2, q);
            }
        }
    }
    __syncthreads();   // feat visible to both waves

    // tail output: bv of last feature = final probs (wave 1, frees wave 0)
    if (t >= 64 && t < 64 + 18) out_tail[b * 18 + (t - 64)] = feat[15 * FSTRIDE + 6 + (t - 64)];

    // ---- build KA/KB: 2048 entries, 16 per thread ----
    for (int n = t; n < 2048; n += 128) {
        int f = n >> 7, r = n & 127;
        int half = r >> 6, a = r & 63;
        const float* fx = &feat[f * FSTRIDE];
        int i0 = (a >> 5) & 1, i1 = (a >> 4) & 1, i2 = (a >> 3) & 1;
        int j0 = (a >> 2) & 1, j1 = (a >> 1) & 1, j2 = a & 1;
        int q = 3 * half;
        float g0 = 1.5f * fx[q], g1 = 1.5f * fx[q + 1], g2 = 1.5f * fx[q + 2];
        const float* bb = fx + 6 + 3 * q;
        float r0, m0, r1, m1, r2, m2;
        rc_entry(g0, bb[0], bb[1], bb[2], i0, j0, r0, m0);
        rc_entry(g1, bb[3], bb[4], bb[5], i1, j1, r1, m1);
        rc_entry(g2, bb[6], bb[7], bb[8], i2, j2, r2, m2);
        float pr = r0 * r1 - m0 * m1, pi = r0 * m1 + m0 * r1;
        float qr = pr * r2 - pi * m2, qi = pr * m2 + pi * r2;
        int row = a >> 3, col = a & 7;
        if (half == 0) {
            // KA: col-major, rows grouped by parity (even at [0..7], odd at [8..15])
            int off = f * KF + col * KSTR + ((row & 1) ? (7 + row) : row);
            sKA[off] = qr; sKA[off + 1] = qi;
        } else {
            int off = f * KF + row * KSTR + 2 * col;
            sKB[off] = qr; sKB[off + 1] = qi;
        }
    }
    __syncthreads();

    // ---- accumulate: out[i][j] = (1/16) sum_f KA[i>>3][j>>3] * KB[i&7][j&7]
    // 128 threads: u=t&15, v0=t>>4 in [0,8); thread covers v = v0 (even KA
    // rows, parity group +0) and v = v0+8 (odd KA rows, parity group +8).
    // baseB identical for both halves since (v0+8)&7 == v0.
    const int u = t & 15, v0 = t >> 4;
    const float* baseA = sKA + (u >> 1) * KSTR;                  // col jA = u>>1
    const float* baseB = sKB + v0 * KSTR + 8 * (u & 1);          // row iB = v0
    float accr[2][4][4], acci[2][4][4];
    #pragma unroll
    for (int h = 0; h < 2; ++h)
        #pragma unroll
        for (int e = 0; e < 4; ++e)
            #pragma unroll
            for (int d = 0; d < 4; ++d) { accr[h][e][d] = 0.0f; acci[h][e][d] = 0.0f; }

    #pragma unroll 2
    for (int f = 0; f < SNAPS; ++f) {
        float4 A0 = *(const float4*)(baseA + f * KF);        // even rows 0,2
        float4 A1 = *(const float4*)(baseA + f * KF + 4);    // even rows 4,6
        float4 A2 = *(const float4*)(baseA + f * KF + 8);    // odd rows 1,3
        float4 A3 = *(const float4*)(baseA + f * KF + 12);   // odd rows 5,7
        float4 B0 = *(const float4*)(baseB + f * KF);
        float4 B1 = *(const float4*)(baseB + f * KF + 4);
        float ar0[4] = {A0.x, A0.z, A1.x, A1.z};   // iA = 2e   (half 0)
        float ai0[4] = {A0.y, A0.w, A1.y, A1.w};
        float ar1[4] = {A2.x, A2.z, A3.x, A3.z};   // iA = 2e+1 (half 1)
        float ai1[4] = {A2.y, A2.w, A3.y, A3.w};
        float br[4]  = {B0.x, B0.z, B1.x, B1.z};   // jB = 4(u&1) + d
        float bi[4]  = {B0.y, B0.w, B1.y, B1.w};
        #pragma unroll
        for (int e = 0; e < 4; ++e)
            #pragma unroll
            for (int d = 0; d < 4; ++d) {
                accr[0][e][d] += ar0[e] * br[d] - ai0[e] * bi[d];
                acci[0][e][d] += ar0[e] * bi[d] + ai0[e] * br[d];
                accr[1][e][d] += ar1[e] * br[d] - ai1[e] * bi[d];
                acci[1][e][d] += ar1[e] * bi[d] + ai1[e] * br[d];
            }
    }

    const float s = 1.0f / 16.0f;
    float* outb = out + (size_t)b * 8192;
    #pragma unroll
    for (int h = 0; h < 2; ++h)
        #pragma unroll
        for (int e = 0; e < 4; ++e) {
            int i = v0 + 8 * h + 16 * e;   // iA = 2e+h, iB = v0
            vfloat4 r4 = { accr[h][e][0] * s, accr[h][e][1] * s, accr[h][e][2] * s, accr[h][e][3] * s };
            vfloat4 i4 = { acci[h][e][0] * s, acci[h][e][1] * s, acci[h][e][2] * s, acci[h][e][3] * s };
            __builtin_nontemporal_store(r4, (vfloat4*)(outb + i * 64 + 4 * u));
            __builtin_nontemporal_store(i4, (vfloat4*)(outb + 4096 + i * 64 + 4 * u));
        }
}

extern "C" void kernel_launch(void* const* d_in, const int* in_sizes, int n_in,
                              void* d_out, int out_size, void* d_ws, size_t ws_size,
                              hipStream_t stream) {
    const float* snapshot = (const float*)d_in[0];
    const float* bcv      = (const float*)d_in[1];
    // d_in[2] = rho — unused: tr(M rho M^dag) = (sum_s p_s^2) tr(rho), tr(rho)=1
    const float* h0       = (const float*)d_in[3];
    const float* c0       = (const float*)d_in[4];
    const float* W_ih     = (const float*)d_in[5];
    const float* W_hh     = (const float*)d_in[6];
    const float* b_ih     = (const float*)d_in[7];
    const float* b_hh     = (const float*)d_in[8];
    const float* Wp       = (const float*)d_in[9];
    const float* bp       = (const float*)d_in[10];
    // d_in[11], d_in[12] = basis_r, basis_i — folded into rc_entry
    float* out = (float*)d_out;

    fused_kernel<<<BATCH, 128, 0, stream>>>(
        snapshot, bcv, h0, c0, W_ih, W_hh, b_ih, b_hh, Wp, bp,
        out, out + (size_t)BATCH * 8192);
}